// Round 2
// 572.142 us; speedup vs baseline: 1.0237x; 1.0237x over previous
//
#include <hip/hip_runtime.h>
#include <math.h>

constexpr int B = 16, D = 128, N = 2048, M = 2048;
#define EPSF 1e-8f

// ---------------------------------------------------------------------------
// K1: logits[b][n][m] = sum_d src_emb[b][d][n] * tgt_emb[b][d][m]
// 128x128 tile per block, 256 threads, 8x8 per thread, BK=8.
// Fragment remap vs round-0: per-thread rows {ty*4+i, 64+ty*4+i}, cols
// {tx*4+j, 64+tx*4+j}. LDS reads become conflict-free:
//   A: 4 unique 16B addrs/wave (16-lane broadcast each) -> free
//   B: 16 unique contiguous 16B addrs, 2 per bank-quad (2-way) -> free (m136)
// Round-0's Bs[kk][tx*8] had 32B stride -> 4 addrs per bank-quad = 4-way
// conflict (the measured 1.68e7 SQ_LDS_BANK_CONFLICT).
// Per-output-element FMA order is unchanged -> logits BIT-IDENTICAL to round-0.
// ---------------------------------------------------------------------------
__global__ __launch_bounds__(256) void gemm_logits(
    const float* __restrict__ Ae, const float* __restrict__ Be,
    float* __restrict__ out)
{
    const int b  = blockIdx.z;
    const int n0 = blockIdx.y * 128;
    const int m0 = blockIdx.x * 128;
    const float* A  = Ae + (size_t)b * D * N;   // A[d][n]
    const float* Bm = Be + (size_t)b * D * M;   // B[d][m]
    float* C = out + (size_t)b * N * M;

    __shared__ float As[8][128];
    __shared__ float Bs[8][128];

    const int t  = threadIdx.x;
    const int lr = t >> 5;          // 0..7  (k-row for staging)
    const int lc = (t & 31) * 4;    // 0..124 (col4 for staging)
    const int tx = t & 15;          // m-dim thread coord
    const int ty = t >> 4;          // n-dim thread coord

    float acc[8][8];
#pragma unroll
    for (int i = 0; i < 8; ++i)
#pragma unroll
        for (int j = 0; j < 8; ++j) acc[i][j] = 0.f;

    for (int d0 = 0; d0 < D; d0 += 8) {
        const float4 av = *(const float4*)(A  + (size_t)(d0 + lr) * N + n0 + lc);
        const float4 bv = *(const float4*)(Bm + (size_t)(d0 + lr) * M + m0 + lc);
        *(float4*)(&As[lr][lc]) = av;
        *(float4*)(&Bs[lr][lc]) = bv;
        __syncthreads();
#pragma unroll
        for (int kk = 0; kk < 8; ++kk) {
            float a[8], bb[8];
            *(float4*)(&a[0])  = *(const float4*)(&As[kk][ty * 4]);
            *(float4*)(&a[4])  = *(const float4*)(&As[kk][64 + ty * 4]);
            *(float4*)(&bb[0]) = *(const float4*)(&Bs[kk][tx * 4]);
            *(float4*)(&bb[4]) = *(const float4*)(&Bs[kk][64 + tx * 4]);
#pragma unroll
            for (int i = 0; i < 8; ++i)
#pragma unroll
                for (int j = 0; j < 8; ++j)
                    acc[i][j] = fmaf(a[i], bb[j], acc[i][j]);
        }
        __syncthreads();
    }

#pragma unroll
    for (int i = 0; i < 8; ++i) {
        const int row = (i < 4) ? (ty * 4 + i) : (64 + ty * 4 + (i - 4));
        float4 c0 = make_float4(acc[i][0], acc[i][1], acc[i][2], acc[i][3]);
        float4 c1 = make_float4(acc[i][4], acc[i][5], acc[i][6], acc[i][7]);
        size_t base = (size_t)(n0 + row) * M + m0;
        *(float4*)(C + base + tx * 4)      = c0;
        *(float4*)(C + base + 64 + tx * 4) = c1;
    }
}

// ---------------------------------------------------------------------------
// K2: per-row softmax (in place), argmax, entropy -> w = -1/(ent+eps)
// one block (256 threads) per row; each thread owns 8 elements.
// VERBATIM round-0 version: w = -1/(ent+eps) is knife-edge sensitive (rows
// with |ent| ~ 1e-8 produce weights ~1e8 whose sign flips on ~1e-9 ent
// perturbations), so the summation order and exp/log implementations must
// stay bit-exact with the known-passing run. Do not "optimize" the math here.
// ---------------------------------------------------------------------------
__global__ __launch_bounds__(256) void softmax_rows(
    float* __restrict__ scores, float* __restrict__ wout, int* __restrict__ idxout)
{
    const int row = blockIdx.x;     // 0..B*N-1
    float* p = scores + (size_t)row * M;
    const int t = threadIdx.x;

    float4 v0 = ((const float4*)p)[t];
    float4 v1 = ((const float4*)p)[t + 256];
    float vals[8] = {v0.x, v0.y, v0.z, v0.w, v1.x, v1.y, v1.z, v1.w};
    int   idxs[8] = {t*4, t*4+1, t*4+2, t*4+3,
                     1024 + t*4, 1024 + t*4 + 1, 1024 + t*4 + 2, 1024 + t*4 + 3};

    // local max + first-occurrence argmax (local indices ascending)
    float m = vals[0]; int mi = idxs[0];
#pragma unroll
    for (int k = 1; k < 8; ++k)
        if (vals[k] > m) { m = vals[k]; mi = idxs[k]; }

    __shared__ float sv[256];
    __shared__ int   si[256];
    sv[t] = m; si[t] = mi;
    __syncthreads();
    for (int s = 128; s > 0; s >>= 1) {
        if (t < s) {
            float ov = sv[t + s]; int oi = si[t + s];
            if (ov > sv[t] || (ov == sv[t] && oi < si[t])) { sv[t] = ov; si[t] = oi; }
        }
        __syncthreads();
    }
    const float rowmax = sv[0];
    const int   rowidx = si[0];
    __syncthreads();

    float e[8]; float lsum = 0.f;
#pragma unroll
    for (int k = 0; k < 8; ++k) { e[k] = expf(vals[k] - rowmax); lsum += e[k]; }
    sv[t] = lsum;
    __syncthreads();
    for (int s = 128; s > 0; s >>= 1) { if (t < s) sv[t] += sv[t + s]; __syncthreads(); }
    const float inv = 1.0f / sv[0];
    __syncthreads();

    float ent = 0.f;
#pragma unroll
    for (int k = 0; k < 8; ++k) {
        float pk = e[k] * inv;
        e[k] = pk;
        ent += pk * logf(pk + EPSF);
    }
    ((float4*)p)[t]       = make_float4(e[0], e[1], e[2], e[3]);
    ((float4*)p)[t + 256] = make_float4(e[4], e[5], e[6], e[7]);

    sv[t] = ent;
    __syncthreads();
    for (int s = 128; s > 0; s >>= 1) { if (t < s) sv[t] += sv[t + s]; __syncthreads(); }
    if (t == 0) {
        wout[row]   = -1.0f / (sv[0] + EPSF);
        idxout[row] = rowidx;
    }
}

// ---------------------------------------------------------------------------
// K3: per-batch weighted Kabsch. 16 blocks x 256 threads (8 points/thread).
// SVD of 3x3 via fp64 Jacobi on H^T H on thread 0.
// VERBATIM round-0 version (reduction order preserved: H feeds the SVD whose
// output is sensitive when one weight dominates and H is near-degenerate).
// ---------------------------------------------------------------------------
__device__ inline float block_sum_256(float v, float* red, int t)
{
    red[t] = v; __syncthreads();
    for (int s = 128; s > 0; s >>= 1) { if (t < s) red[t] += red[t + s]; __syncthreads(); }
    float r = red[0]; __syncthreads();
    return r;
}

__global__ __launch_bounds__(256) void kabsch(
    const float* __restrict__ src, const float* __restrict__ tgt,
    const float* __restrict__ wraw, const int* __restrict__ idxv,
    float* __restrict__ Rout, float* __restrict__ tout)
{
    const int b = blockIdx.x;
    const int t = threadIdx.x;
    const float* S  = src  + (size_t)b * 3 * N;
    const float* T  = tgt  + (size_t)b * 3 * M;
    const float* w  = wraw + (size_t)b * N;
    const int*  idx = idxv + (size_t)b * N;

    __shared__ float red[256];

    float w8[8]; int i8[8];
    float s8[8][3], g8[8][3];
    float lsum = 0.f;
#pragma unroll
    for (int k = 0; k < 8; ++k) {
        int n = t + 256 * k;
        w8[k] = w[n];
        i8[k] = idx[n];
        lsum += w8[k];
#pragma unroll
        for (int i = 0; i < 3; ++i) {
            s8[k][i] = S[i * N + n];
            g8[k][i] = T[i * M + i8[k]];
        }
    }
    const float W = block_sum_256(lsum, red, t) + EPSF;

    // centroids
    float c[6] = {0, 0, 0, 0, 0, 0};
#pragma unroll
    for (int k = 0; k < 8; ++k) {
        float wn = w8[k] / W;
#pragma unroll
        for (int i = 0; i < 3; ++i) {
            c[i]     += wn * s8[k][i];
            c[3 + i] += wn * g8[k][i];
        }
    }
    float cen[6];
    for (int i = 0; i < 6; ++i) cen[i] = block_sum_256(c[i], red, t);

    // H accumulation
    float h[9] = {0};
#pragma unroll
    for (int k = 0; k < 8; ++k) {
        float wn = w8[k] / W;
        float a0 = s8[k][0] - cen[0], a1 = s8[k][1] - cen[1], a2 = s8[k][2] - cen[2];
        float b0 = (g8[k][0] - cen[3]) * wn;
        float b1 = (g8[k][1] - cen[4]) * wn;
        float b2 = (g8[k][2] - cen[5]) * wn;
        h[0] += a0 * b0; h[1] += a0 * b1; h[2] += a0 * b2;
        h[3] += a1 * b0; h[4] += a1 * b1; h[5] += a1 * b2;
        h[6] += a2 * b0; h[7] += a2 * b1; h[8] += a2 * b2;
    }
    float hr[9];
    for (int i = 0; i < 9; ++i) hr[i] = block_sum_256(h[i], red, t);

    if (t == 0) {
        double H[3][3];
        for (int i = 0; i < 3; ++i)
            for (int j = 0; j < 3; ++j)
                H[i][j] = (double)hr[i * 3 + j] + (i == j ? 1e-8 : 0.0);

        // A = H^T H (symmetric PSD)
        double A[3][3];
        for (int i = 0; i < 3; ++i)
            for (int j = 0; j < 3; ++j)
                A[i][j] = H[0][i] * H[0][j] + H[1][i] * H[1][j] + H[2][i] * H[2][j];

        double V[3][3] = {{1, 0, 0}, {0, 1, 0}, {0, 0, 1}};
        const int PP[3] = {0, 0, 1}, QQ[3] = {1, 2, 2};
        for (int sweep = 0; sweep < 30; ++sweep) {
            for (int r = 0; r < 3; ++r) {
                int p = PP[r], q = QQ[r];
                double apq = A[p][q];
                if (fabs(apq) < 1e-300) continue;
                double theta = (A[q][q] - A[p][p]) / (2.0 * apq);
                double tt = (theta >= 0 ? 1.0 : -1.0) /
                            (fabs(theta) + sqrt(theta * theta + 1.0));
                double cc = 1.0 / sqrt(tt * tt + 1.0);
                double ss = tt * cc;
                for (int k = 0; k < 3; ++k) {   // A <- A J
                    double akp = A[k][p], akq = A[k][q];
                    A[k][p] = cc * akp - ss * akq;
                    A[k][q] = ss * akp + cc * akq;
                }
                for (int k = 0; k < 3; ++k) {   // A <- J^T A
                    double apk = A[p][k], aqk = A[q][k];
                    A[p][k] = cc * apk - ss * aqk;
                    A[q][k] = ss * apk + cc * aqk;
                }
                for (int k = 0; k < 3; ++k) {   // V <- V J
                    double vkp = V[k][p], vkq = V[k][q];
                    V[k][p] = cc * vkp - ss * vkq;
                    V[k][q] = ss * vkp + cc * vkq;
                }
            }
        }
        // sort eigenvalues descending, permute V columns
        double ev[3] = {A[0][0], A[1][1], A[2][2]};
        int ord[3] = {0, 1, 2};
        for (int i = 0; i < 2; ++i)
            for (int j = i + 1; j < 3; ++j)
                if (ev[ord[j]] > ev[ord[i]]) { int tmp = ord[i]; ord[i] = ord[j]; ord[j] = tmp; }
        double Vs[3][3];
        for (int i = 0; i < 3; ++i)
            for (int j = 0; j < 3; ++j)
                Vs[i][j] = V[i][ord[j]];

        // U columns: u_j = H v_j / s_j with Gram-Schmidt fallback
        double U[3][3];
        for (int j = 0; j < 2; ++j) {
            double u0 = H[0][0] * Vs[0][j] + H[0][1] * Vs[1][j] + H[0][2] * Vs[2][j];
            double u1 = H[1][0] * Vs[0][j] + H[1][1] * Vs[1][j] + H[1][2] * Vs[2][j];
            double u2 = H[2][0] * Vs[0][j] + H[2][1] * Vs[1][j] + H[2][2] * Vs[2][j];
            if (j == 1) {   // re-orthogonalize against u_0
                double d0 = u0 * U[0][0] + u1 * U[1][0] + u2 * U[2][0];
                u0 -= d0 * U[0][0]; u1 -= d0 * U[1][0]; u2 -= d0 * U[2][0];
            }
            double nn = sqrt(u0 * u0 + u1 * u1 + u2 * u2);
            if (nn < 1e-150) {  // degenerate: pick any unit vector orth. to previous
                u0 = (j == 0) ? 1.0 : -U[1][0];
                u1 = (j == 0) ? 0.0 : U[0][0];
                u2 = 0.0;
                nn = sqrt(u0 * u0 + u1 * u1 + u2 * u2);
                if (nn < 1e-150) { u0 = 0; u1 = 0; u2 = 1; nn = 1; }
            }
            U[0][j] = u0 / nn; U[1][j] = u1 / nn; U[2][j] = u2 / nn;
        }
        // u_2 = u_0 x u_1  (sign of 3rd column cancels in R)
        U[0][2] = U[1][0] * U[2][1] - U[2][0] * U[1][1];
        U[1][2] = U[2][0] * U[0][1] - U[0][0] * U[2][1];
        U[2][2] = U[0][0] * U[1][1] - U[1][0] * U[0][1];

        // r = V U^T ; d = det(r)
        double r[3][3];
        for (int i = 0; i < 3; ++i)
            for (int j = 0; j < 3; ++j)
                r[i][j] = Vs[i][0] * U[j][0] + Vs[i][1] * U[j][1] + Vs[i][2] * U[j][2];
        double det = r[0][0] * (r[1][1] * r[2][2] - r[1][2] * r[2][1])
                   - r[0][1] * (r[1][0] * r[2][2] - r[1][2] * r[2][0])
                   + r[0][2] * (r[1][0] * r[2][1] - r[1][1] * r[2][0]);

        // R = V diag(1,1,det) U^T
        double R[3][3];
        for (int i = 0; i < 3; ++i)
            for (int j = 0; j < 3; ++j)
                R[i][j] = Vs[i][0] * U[j][0] + Vs[i][1] * U[j][1] + det * Vs[i][2] * U[j][2];

        // t = tgt_centroid - R * src_centroid
        double tv[3];
        for (int i = 0; i < 3; ++i)
            tv[i] = (double)cen[3 + i]
                  - (R[i][0] * cen[0] + R[i][1] * cen[1] + R[i][2] * cen[2]);

        for (int i = 0; i < 3; ++i)
            for (int j = 0; j < 3; ++j)
                Rout[b * 9 + i * 3 + j] = (float)R[i][j];
        for (int i = 0; i < 3; ++i)
            tout[b * 3 + i] = (float)tv[i];
    }
}

// ---------------------------------------------------------------------------
extern "C" void kernel_launch(void* const* d_in, const int* in_sizes, int n_in,
                              void* d_out, int out_size, void* d_ws, size_t ws_size,
                              hipStream_t stream)
{
    const float* src_emb = (const float*)d_in[0];   // (B, D, N)
    const float* tgt_emb = (const float*)d_in[1];   // (B, D, M)
    const float* src     = (const float*)d_in[2];   // (B, 3, N)
    const float* tgt     = (const float*)d_in[3];   // (B, 3, M)
    // d_in[4] = temperature: unused by the reference.

    float* out    = (float*)d_out;
    float* Rout   = out;                 // B*9   = 144
    float* tout   = out + B * 9;         // B*3   = 48
    float* scores = out + B * 12;        // B*N*M (16B-aligned: 192 floats)

    float* wws   = (float*)d_ws;                     // B*N floats
    int*   idxws = (int*)((float*)d_ws + B * N);     // B*N ints

    dim3 g1(M / 128, N / 128, B);
    gemm_logits<<<g1, 256, 0, stream>>>(src_emb, tgt_emb, scores);
    softmax_rows<<<B * N, 256, 0, stream>>>(scores, wws, idxws);
    kabsch<<<B, 256, 0, stream>>>(src, tgt, wws, idxws, Rout, tout);
}

// Round 3
// 562.463 us; speedup vs baseline: 1.0413x; 1.0172x over previous
//
#include <hip/hip_runtime.h>
#include <math.h>

constexpr int B = 16, D = 128, N = 2048, M = 2048;
#define EPSF 1e-8f

// ---------------------------------------------------------------------------
// K1: logits[b][n][m] = sum_d src_emb[b][d][n] * tgt_emb[b][d][m]
// 128x128 tile per block, 256 threads, 8x8 per thread, BK=8.
// LDS layout conflict-free (round-2). NEW: register prefetch of the next
// K-tile issued right after the first barrier, so global-load latency hides
// under the 8-kk compute instead of serializing with the LDS store+barrier.
// Same addresses, same per-output FMA order -> logits BIT-IDENTICAL.
// ---------------------------------------------------------------------------
__global__ __launch_bounds__(256) void gemm_logits(
    const float* __restrict__ Ae, const float* __restrict__ Be,
    float* __restrict__ out)
{
    const int b  = blockIdx.z;
    const int n0 = blockIdx.y * 128;
    const int m0 = blockIdx.x * 128;
    const float* A  = Ae + (size_t)b * D * N;   // A[d][n]
    const float* Bm = Be + (size_t)b * D * M;   // B[d][m]
    float* C = out + (size_t)b * N * M;

    __shared__ float As[8][128];
    __shared__ float Bs[8][128];

    const int t  = threadIdx.x;
    const int lr = t >> 5;          // 0..7  (k-row for staging)
    const int lc = (t & 31) * 4;    // 0..124 (col4 for staging)
    const int tx = t & 15;          // m-dim thread coord
    const int ty = t >> 4;          // n-dim thread coord

    const float* Aptr = A  + (size_t)lr * N + n0 + lc;
    const float* Bptr = Bm + (size_t)lr * M + m0 + lc;

    float acc[8][8];
#pragma unroll
    for (int i = 0; i < 8; ++i)
#pragma unroll
        for (int j = 0; j < 8; ++j) acc[i][j] = 0.f;

    float4 av = *(const float4*)(Aptr);
    float4 bv = *(const float4*)(Bptr);

    for (int d0 = 0; d0 < D; d0 += 8) {
        *(float4*)(&As[lr][lc]) = av;
        *(float4*)(&Bs[lr][lc]) = bv;
        __syncthreads();
        if (d0 + 8 < D) {           // prefetch next K-tile under the compute
            av = *(const float4*)(Aptr + (size_t)(d0 + 8) * N);
            bv = *(const float4*)(Bptr + (size_t)(d0 + 8) * M);
        }
#pragma unroll
        for (int kk = 0; kk < 8; ++kk) {
            float a[8], bb[8];
            *(float4*)(&a[0])  = *(const float4*)(&As[kk][ty * 4]);
            *(float4*)(&a[4])  = *(const float4*)(&As[kk][64 + ty * 4]);
            *(float4*)(&bb[0]) = *(const float4*)(&Bs[kk][tx * 4]);
            *(float4*)(&bb[4]) = *(const float4*)(&Bs[kk][64 + tx * 4]);
#pragma unroll
            for (int i = 0; i < 8; ++i)
#pragma unroll
                for (int j = 0; j < 8; ++j)
                    acc[i][j] = fmaf(a[i], bb[j], acc[i][j]);
        }
        __syncthreads();
    }

#pragma unroll
    for (int i = 0; i < 8; ++i) {
        const int row = (i < 4) ? (ty * 4 + i) : (64 + ty * 4 + (i - 4));
        float4 c0 = make_float4(acc[i][0], acc[i][1], acc[i][2], acc[i][3]);
        float4 c1 = make_float4(acc[i][4], acc[i][5], acc[i][6], acc[i][7]);
        size_t base = (size_t)(n0 + row) * M + m0;
        *(float4*)(C + base + tx * 4)      = c0;
        *(float4*)(C + base + 64 + tx * 4) = c1;
    }
}

// ---------------------------------------------------------------------------
// K2: per-row softmax (in place), argmax, entropy -> w = -1/(ent+eps)
// one block (256 threads) per row; each thread owns 8 elements.
// BIT-EXACT CONSTRAINT: w = -1/(ent+eps) is knife-edge sensitive; the
// arithmetic DAG (operand pairing + order of every add/compare, expf/logf
// implementations) is IDENTICAL to the round-0 LDS tree. Only the transport
// changed: steps s=128,64 via two LDS exchanges, steps s=32..1 via
// __shfl_down inside wave 0 (v = v + shfl_down(v,s) pairs lane t with lane
// t+s — exactly the tree's sv[t] += sv[t+s]). 28 barriers -> 8.
// ---------------------------------------------------------------------------
__global__ __launch_bounds__(256) void softmax_rows(
    float* __restrict__ scores, float* __restrict__ wout, int* __restrict__ idxout)
{
    const int row = blockIdx.x;     // 0..B*N-1
    float* p = scores + (size_t)row * M;
    const int t = threadIdx.x;
    const int wid = t >> 6;

    float4 v0 = ((const float4*)p)[t];
    float4 v1 = ((const float4*)p)[t + 256];
    float vals[8] = {v0.x, v0.y, v0.z, v0.w, v1.x, v1.y, v1.z, v1.w};
    int   idxs[8] = {t*4, t*4+1, t*4+2, t*4+3,
                     1024 + t*4, 1024 + t*4 + 1, 1024 + t*4 + 2, 1024 + t*4 + 3};

    // local max + first-occurrence argmax (local indices ascending)
    float m = vals[0]; int mi = idxs[0];
#pragma unroll
    for (int k = 1; k < 8; ++k)
        if (vals[k] > m) { m = vals[k]; mi = idxs[k]; }

    __shared__ float sv[256];
    __shared__ int   si[256];
    __shared__ float resf[2];
    __shared__ int   resi;

    // ---- max/argmax hybrid tree (pairing identical to LDS tree) ----
    sv[t] = m; si[t] = mi;
    __syncthreads();
    if (t < 128) {                               // step s=128
        float ov = sv[t + 128]; int oi = si[t + 128];
        if (ov > m || (ov == m && oi < mi)) { m = ov; mi = oi; }
    }
    if (wid == 1) { sv[t] = m; si[t] = mi; }     // publish wave-1 partials
    __syncthreads();
    if (t < 64) {
        float ov = sv[t + 64]; int oi = si[t + 64];   // step s=64
        if (ov > m || (ov == m && oi < mi)) { m = ov; mi = oi; }
#pragma unroll
        for (int s = 32; s > 0; s >>= 1) {            // steps s=32..1
            float om = __shfl_down(m, s);
            int   oi2 = __shfl_down(mi, s);
            if (om > m || (om == m && oi2 < mi)) { m = om; mi = oi2; }
        }
        if (t == 0) { resf[0] = m; resi = mi; }
    }
    __syncthreads();
    const float rowmax = resf[0];
    const int   rowidx = resi;

    // ---- exp + sum (same expf, same add order) ----
    float e[8]; float lsum = 0.f;
#pragma unroll
    for (int k = 0; k < 8; ++k) { e[k] = expf(vals[k] - rowmax); lsum += e[k]; }
    sv[t] = lsum;
    __syncthreads();
    float sum = lsum;
    if (t < 128) sum = sum + sv[t + 128];
    if (wid == 1) sv[t] = sum;
    __syncthreads();
    if (t < 64) {
        sum = sum + sv[t + 64];
#pragma unroll
        for (int s = 32; s > 0; s >>= 1) sum = sum + __shfl_down(sum, s);
        if (t == 0) resf[1] = sum;
    }
    __syncthreads();
    const float inv = 1.0f / resf[1];

    // ---- normalize + entropy (same logf, same order) ----
    float ent = 0.f;
#pragma unroll
    for (int k = 0; k < 8; ++k) {
        float pk = e[k] * inv;
        e[k] = pk;
        ent += pk * logf(pk + EPSF);
    }
    ((float4*)p)[t]       = make_float4(e[0], e[1], e[2], e[3]);
    ((float4*)p)[t + 256] = make_float4(e[4], e[5], e[6], e[7]);

    sv[t] = ent;
    __syncthreads();
    if (t < 128) ent = ent + sv[t + 128];
    if (wid == 1) sv[t] = ent;
    __syncthreads();
    if (t < 64) {
        ent = ent + sv[t + 64];
#pragma unroll
        for (int s = 32; s > 0; s >>= 1) ent = ent + __shfl_down(ent, s);
        if (t == 0) {
            wout[row]   = -1.0f / (ent + EPSF);
            idxout[row] = rowidx;
        }
    }
}

// ---------------------------------------------------------------------------
// K3: per-batch weighted Kabsch. 16 blocks x 256 threads (8 points/thread).
// BIT-EXACT: each of the 16 reduction trees keeps the exact block_sum_256
// pairing; independent trees within a group are BATCHED through shared
// barriers (W:1, centroids:6, H:9) -> ~144 barriers -> ~9.
// SVD of 3x3 via fp64 Jacobi on H^T H on thread 0 (verbatim).
// ---------------------------------------------------------------------------
template <int Q>
__device__ inline void block_sum_hybrid(float (&v)[Q], float (*red)[256],
                                        float* res, int t, int wid)
{
#pragma unroll
    for (int q = 0; q < Q; ++q) red[q][t] = v[q];
    __syncthreads();
    if (t < 128) {
#pragma unroll
        for (int q = 0; q < Q; ++q) v[q] += red[q][t + 128];
    }
    if (wid == 1) {
#pragma unroll
        for (int q = 0; q < Q; ++q) red[q][t] = v[q];
    }
    __syncthreads();
    if (t < 64) {
#pragma unroll
        for (int q = 0; q < Q; ++q) v[q] += red[q][t + 64];
#pragma unroll
        for (int s = 32; s > 0; s >>= 1)
#pragma unroll
            for (int q = 0; q < Q; ++q) v[q] += __shfl_down(v[q], s);
        if (t == 0) {
#pragma unroll
            for (int q = 0; q < Q; ++q) res[q] = v[q];
        }
    }
    __syncthreads();
#pragma unroll
    for (int q = 0; q < Q; ++q) v[q] = res[q];
}

__global__ __launch_bounds__(256) void kabsch(
    const float* __restrict__ src, const float* __restrict__ tgt,
    const float* __restrict__ wraw, const int* __restrict__ idxv,
    float* __restrict__ Rout, float* __restrict__ tout)
{
    const int b = blockIdx.x;
    const int t = threadIdx.x;
    const int wid = t >> 6;
    const float* S  = src  + (size_t)b * 3 * N;
    const float* T  = tgt  + (size_t)b * 3 * M;
    const float* w  = wraw + (size_t)b * N;
    const int*  idx = idxv + (size_t)b * N;

    __shared__ float red[9][256];
    __shared__ float res[9];

    float w8[8]; int i8[8];
    float s8[8][3], g8[8][3];
    float lsum[1] = {0.f};
#pragma unroll
    for (int k = 0; k < 8; ++k) {
        int n = t + 256 * k;
        w8[k] = w[n];
        i8[k] = idx[n];
        lsum[0] += w8[k];
#pragma unroll
        for (int i = 0; i < 3; ++i) {
            s8[k][i] = S[i * N + n];
            g8[k][i] = T[i * M + i8[k]];
        }
    }
    block_sum_hybrid<1>(lsum, red, res, t, wid);
    const float W = lsum[0] + EPSF;

    // centroids (same per-k accumulation order, 6 trees batched)
    float c[6] = {0, 0, 0, 0, 0, 0};
#pragma unroll
    for (int k = 0; k < 8; ++k) {
        float wn = w8[k] / W;
#pragma unroll
        for (int i = 0; i < 3; ++i) {
            c[i]     += wn * s8[k][i];
            c[3 + i] += wn * g8[k][i];
        }
    }
    block_sum_hybrid<6>(c, red, res, t, wid);
    float cen[6];
#pragma unroll
    for (int i = 0; i < 6; ++i) cen[i] = c[i];

    // H accumulation (verbatim order, 9 trees batched)
    float h[9] = {0};
#pragma unroll
    for (int k = 0; k < 8; ++k) {
        float wn = w8[k] / W;
        float a0 = s8[k][0] - cen[0], a1 = s8[k][1] - cen[1], a2 = s8[k][2] - cen[2];
        float b0 = (g8[k][0] - cen[3]) * wn;
        float b1 = (g8[k][1] - cen[4]) * wn;
        float b2 = (g8[k][2] - cen[5]) * wn;
        h[0] += a0 * b0; h[1] += a0 * b1; h[2] += a0 * b2;
        h[3] += a1 * b0; h[4] += a1 * b1; h[5] += a1 * b2;
        h[6] += a2 * b0; h[7] += a2 * b1; h[8] += a2 * b2;
    }
    block_sum_hybrid<9>(h, red, res, t, wid);

    if (t == 0) {
        float hr[9];
#pragma unroll
        for (int q = 0; q < 9; ++q) hr[q] = h[q];

        double H[3][3];
        for (int i = 0; i < 3; ++i)
            for (int j = 0; j < 3; ++j)
                H[i][j] = (double)hr[i * 3 + j] + (i == j ? 1e-8 : 0.0);

        // A = H^T H (symmetric PSD)
        double A[3][3];
        for (int i = 0; i < 3; ++i)
            for (int j = 0; j < 3; ++j)
                A[i][j] = H[0][i] * H[0][j] + H[1][i] * H[1][j] + H[2][i] * H[2][j];

        double V[3][3] = {{1, 0, 0}, {0, 1, 0}, {0, 0, 1}};
        const int PP[3] = {0, 0, 1}, QQ[3] = {1, 2, 2};
        for (int sweep = 0; sweep < 30; ++sweep) {
            for (int r = 0; r < 3; ++r) {
                int p = PP[r], q = QQ[r];
                double apq = A[p][q];
                if (fabs(apq) < 1e-300) continue;
                double theta = (A[q][q] - A[p][p]) / (2.0 * apq);
                double tt = (theta >= 0 ? 1.0 : -1.0) /
                            (fabs(theta) + sqrt(theta * theta + 1.0));
                double cc = 1.0 / sqrt(tt * tt + 1.0);
                double ss = tt * cc;
                for (int k = 0; k < 3; ++k) {   // A <- A J
                    double akp = A[k][p], akq = A[k][q];
                    A[k][p] = cc * akp - ss * akq;
                    A[k][q] = ss * akp + cc * akq;
                }
                for (int k = 0; k < 3; ++k) {   // A <- J^T A
                    double apk = A[p][k], aqk = A[q][k];
                    A[p][k] = cc * apk - ss * aqk;
                    A[q][k] = ss * apk + cc * aqk;
                }
                for (int k = 0; k < 3; ++k) {   // V <- V J
                    double vkp = V[k][p], vkq = V[k][q];
                    V[k][p] = cc * vkp - ss * vkq;
                    V[k][q] = ss * vkp + cc * vkq;
                }
            }
        }
        // sort eigenvalues descending, permute V columns
        double ev[3] = {A[0][0], A[1][1], A[2][2]};
        int ord[3] = {0, 1, 2};
        for (int i = 0; i < 2; ++i)
            for (int j = i + 1; j < 3; ++j)
                if (ev[ord[j]] > ev[ord[i]]) { int tmp = ord[i]; ord[i] = ord[j]; ord[j] = tmp; }
        double Vs[3][3];
        for (int i = 0; i < 3; ++i)
            for (int j = 0; j < 3; ++j)
                Vs[i][j] = V[i][ord[j]];

        // U columns: u_j = H v_j / s_j with Gram-Schmidt fallback
        double U[3][3];
        for (int j = 0; j < 2; ++j) {
            double u0 = H[0][0] * Vs[0][j] + H[0][1] * Vs[1][j] + H[0][2] * Vs[2][j];
            double u1 = H[1][0] * Vs[0][j] + H[1][1] * Vs[1][j] + H[1][2] * Vs[2][j];
            double u2 = H[2][0] * Vs[0][j] + H[2][1] * Vs[1][j] + H[2][2] * Vs[2][j];
            if (j == 1) {   // re-orthogonalize against u_0
                double d0 = u0 * U[0][0] + u1 * U[1][0] + u2 * U[2][0];
                u0 -= d0 * U[0][0]; u1 -= d0 * U[1][0]; u2 -= d0 * U[2][0];
            }
            double nn = sqrt(u0 * u0 + u1 * u1 + u2 * u2);
            if (nn < 1e-150) {  // degenerate: pick any unit vector orth. to previous
                u0 = (j == 0) ? 1.0 : -U[1][0];
                u1 = (j == 0) ? 0.0 : U[0][0];
                u2 = 0.0;
                nn = sqrt(u0 * u0 + u1 * u1 + u2 * u2);
                if (nn < 1e-150) { u0 = 0; u1 = 0; u2 = 1; nn = 1; }
            }
            U[0][j] = u0 / nn; U[1][j] = u1 / nn; U[2][j] = u2 / nn;
        }
        // u_2 = u_0 x u_1  (sign of 3rd column cancels in R)
        U[0][2] = U[1][0] * U[2][1] - U[2][0] * U[1][1];
        U[1][2] = U[2][0] * U[0][1] - U[0][0] * U[2][1];
        U[2][2] = U[0][0] * U[1][1] - U[1][0] * U[0][1];

        // r = V U^T ; d = det(r)
        double r[3][3];
        for (int i = 0; i < 3; ++i)
            for (int j = 0; j < 3; ++j)
                r[i][j] = Vs[i][0] * U[j][0] + Vs[i][1] * U[j][1] + Vs[i][2] * U[j][2];
        double det = r[0][0] * (r[1][1] * r[2][2] - r[1][2] * r[2][1])
                   - r[0][1] * (r[1][0] * r[2][2] - r[1][2] * r[2][0])
                   + r[0][2] * (r[1][0] * r[2][1] - r[1][1] * r[2][0]);

        // R = V diag(1,1,det) U^T
        double R[3][3];
        for (int i = 0; i < 3; ++i)
            for (int j = 0; j < 3; ++j)
                R[i][j] = Vs[i][0] * U[j][0] + Vs[i][1] * U[j][1] + det * Vs[i][2] * U[j][2];

        // t = tgt_centroid - R * src_centroid
        double tv[3];
        for (int i = 0; i < 3; ++i)
            tv[i] = (double)cen[3 + i]
                  - (R[i][0] * cen[0] + R[i][1] * cen[1] + R[i][2] * cen[2]);

        for (int i = 0; i < 3; ++i)
            for (int j = 0; j < 3; ++j)
                Rout[b * 9 + i * 3 + j] = (float)R[i][j];
        for (int i = 0; i < 3; ++i)
            tout[b * 3 + i] = (float)tv[i];
    }
}

// ---------------------------------------------------------------------------
extern "C" void kernel_launch(void* const* d_in, const int* in_sizes, int n_in,
                              void* d_out, int out_size, void* d_ws, size_t ws_size,
                              hipStream_t stream)
{
    const float* src_emb = (const float*)d_in[0];   // (B, D, N)
    const float* tgt_emb = (const float*)d_in[1];   // (B, D, M)
    const float* src     = (const float*)d_in[2];   // (B, 3, N)
    const float* tgt     = (const float*)d_in[3];   // (B, 3, M)
    // d_in[4] = temperature: unused by the reference.

    float* out    = (float*)d_out;
    float* Rout   = out;                 // B*9   = 144
    float* tout   = out + B * 9;         // B*3   = 48
    float* scores = out + B * 12;        // B*N*M (16B-aligned: 192 floats)

    float* wws   = (float*)d_ws;                     // B*N floats
    int*   idxws = (int*)((float*)d_ws + B * N);     // B*N ints

    dim3 g1(M / 128, N / 128, B);
    gemm_logits<<<g1, 256, 0, stream>>>(src_emb, tgt_emb, scores);
    softmax_rows<<<B * N, 256, 0, stream>>>(scores, wws, idxws);
    kabsch<<<B, 256, 0, stream>>>(src, tgt, wws, idxws, Rout, tout);
}